// Round 1
// baseline (219.977 us; speedup 1.0000x reference)
//
#include <hip/hip_runtime.h>

#define BSZ 2
#define CIN 32
#define COUT 64
#define DD_ 8
#define HH_ 48
#define WW_ 48
#define KK 27
#define HWs (HH_*WW_)
#define DHW (DD_*HH_*WW_)

// Pre-transpose weight (Cout, Cin, K) -> wT (K, Cin, Cout) for coalesced staging.
__global__ void transpose_w(const float* __restrict__ w, float* __restrict__ wT) {
    int e = blockIdx.x * 256 + threadIdx.x;
    if (e >= COUT * CIN * KK) return;
    int co = e & 63;
    int t  = e >> 6;       // k*CIN + ci
    int ci = t & 31;
    int k  = t >> 5;
    wT[e] = w[(co * CIN + ci) * KK + k];
}

__launch_bounds__(256, 2)
__global__ void dcn3d(const float* __restrict__ x, const float* __restrict__ off,
                      const float* __restrict__ msk, const float* __restrict__ wsrc,
                      const float* __restrict__ bias, float* __restrict__ out,
                      int wsrc_is_transposed) {
    // block -> (b, d, h)
    int blk = blockIdx.x;
    int h = blk % HH_;
    int t = blk / HH_;
    int d = t % DD_;
    int b = t / DD_;

    __shared__ float pw00[KK * WW_], pw01[KK * WW_], pw10[KK * WW_], pw11[KK * WW_];
    __shared__ int   po00[KK * WW_], po01[KK * WW_], po10[KK * WW_], po11[KK * WW_];
    __shared__ float S[CIN][WW_];
    __shared__ float WL[CIN * COUT];

    int tid = threadIdx.x;

    // ---- Phase A: per-(k, w) bilinear parameters ----
    for (int e = tid; e < KK * WW_; e += 256) {
        int k = e / WW_;
        int w = e - k * WW_;
        int kd = k / 9, kh = (k / 3) % 3, kw = k % 3;
        int dpos = d + kd - 1;
        bool vd = (dpos >= 0) && (dpos < DD_);
        int didx = min(max(dpos, 0), DD_ - 1);
        int sp = d * HWs + h * WW_ + w;
        int obase = (b * (2 * KK) + 2 * k) * DHW + sp;
        float oh = off[obase];
        float ow = off[obase + DHW];
        float m  = msk[(b * KK + k) * DHW + sp];
        float hh = (float)(kh + h - 1) + oh;
        float ww = (float)(kw + w - 1) + ow;
        float h0f = floorf(hh), w0f = floorf(ww);
        float lh = hh - h0f, lw = ww - w0f;
        int h0 = (int)h0f, w0 = (int)w0f;
        int h1 = h0 + 1, w1 = w0 + 1;
        bool ih0 = (h0 >= 0) && (h0 < HH_);
        bool ih1 = (h1 >= 0) && (h1 < HH_);
        bool iw0 = (w0 >= 0) && (w0 < WW_);
        bool iw1 = (w1 >= 0) && (w1 < WW_);
        int h0c = min(max(h0, 0), HH_ - 1), h1c = min(max(h1, 0), HH_ - 1);
        int w0c = min(max(w0, 0), WW_ - 1), w1c = min(max(w1, 0), WW_ - 1);
        float vm = vd ? m : 0.0f;
        pw00[e] = (ih0 && iw0) ? (1.0f - lh) * (1.0f - lw) * vm : 0.0f;
        pw01[e] = (ih0 && iw1) ? (1.0f - lh) * lw * vm : 0.0f;
        pw10[e] = (ih1 && iw0) ? lh * (1.0f - lw) * vm : 0.0f;
        pw11[e] = (ih1 && iw1) ? lh * lw * vm : 0.0f;
        int r0 = didx * HWs + h0c * WW_;
        int r1 = didx * HWs + h1c * WW_;
        po00[e] = r0 + w0c;
        po01[e] = r0 + w1c;
        po10[e] = r1 + w0c;
        po11[e] = r1 + w1c;
    }

    float acc[4][3];
#pragma unroll
    for (int c = 0; c < 4; ++c)
#pragma unroll
        for (int j = 0; j < 3; ++j) acc[c][j] = 0.0f;

    int cog = (tid & 15) * 4;   // co base (0..60)
    int ng  = (tid >> 4) * 3;   // n (=w) base (0..45)

    const float* xb = x + b * CIN * DHW;

    for (int k = 0; k < KK; ++k) {
        __syncthreads();  // phase A done / previous GEMM reads done
        // stage weight slice WL[ci*64+co]
        if (wsrc_is_transposed) {
            for (int e = tid; e < CIN * COUT; e += 256)
                WL[e] = wsrc[k * CIN * COUT + e];
        } else {
            for (int e = tid; e < CIN * COUT; e += 256) {
                int ci = e >> 6, co = e & 63;
                WL[e] = wsrc[(co * CIN + ci) * KK + k];
            }
        }
        // sample S_k[ci][w]
        for (int e = tid; e < CIN * WW_; e += 256) {
            int ci = e / WW_;
            int w  = e - ci * WW_;
            int p  = k * WW_ + w;
            const float* xp = xb + ci * DHW;
            float v = pw00[p] * xp[po00[p]] + pw01[p] * xp[po01[p]]
                    + pw10[p] * xp[po10[p]] + pw11[p] * xp[po11[p]];
            S[ci][w] = v;
        }
        __syncthreads();
        // mini-GEMM: acc[4co][3n] += WL[ci][co] * S[ci][n]
#pragma unroll 4
        for (int ci = 0; ci < CIN; ++ci) {
            float4 wv = *(const float4*)&WL[ci * COUT + cog];
            float s0 = S[ci][ng];
            float s1 = S[ci][ng + 1];
            float s2 = S[ci][ng + 2];
            acc[0][0] += wv.x * s0; acc[0][1] += wv.x * s1; acc[0][2] += wv.x * s2;
            acc[1][0] += wv.y * s0; acc[1][1] += wv.y * s1; acc[1][2] += wv.y * s2;
            acc[2][0] += wv.z * s0; acc[2][1] += wv.z * s1; acc[2][2] += wv.z * s2;
            acc[3][0] += wv.w * s0; acc[3][1] += wv.w * s1; acc[3][2] += wv.w * s2;
        }
    }

    // epilogue: bias + store
#pragma unroll
    for (int c = 0; c < 4; ++c) {
        float bv = bias[cog + c];
        int ob = ((b * COUT + cog + c) * DD_ + d) * HWs + h * WW_ + ng;
#pragma unroll
        for (int j = 0; j < 3; ++j)
            out[ob + j] = acc[c][j] + bv;
    }
}

extern "C" void kernel_launch(void* const* d_in, const int* in_sizes, int n_in,
                              void* d_out, int out_size, void* d_ws, size_t ws_size,
                              hipStream_t stream) {
    const float* x    = (const float*)d_in[0];
    const float* off  = (const float*)d_in[1];
    const float* msk  = (const float*)d_in[2];
    const float* w    = (const float*)d_in[3];
    const float* bias = (const float*)d_in[4];
    float* out = (float*)d_out;

    int use_t = (ws_size >= (size_t)(COUT * CIN * KK * 4)) ? 1 : 0;
    const float* wsrc = w;
    if (use_t) {
        transpose_w<<<(COUT * CIN * KK + 255) / 256, 256, 0, stream>>>(w, (float*)d_ws);
        wsrc = (const float*)d_ws;
    }
    dcn3d<<<BSZ * DD_ * HH_, 256, 0, stream>>>(x, off, msk, wsrc, bias, out, use_t);
}

// Round 2
// 101.176 us; speedup vs baseline: 2.1742x; 2.1742x over previous
//
#include <hip/hip_runtime.h>
#include <hip/hip_bf16.h>
#include <hip/hip_fp16.h>

#define BSZ 2
#define CIN 32
#define COUT 64
#define DD_ 8
#define HH_ 48
#define WW_ 48
#define KK 27
#define HWs (HH_*WW_)
#define DHW (DD_*HH_*WW_)
#define NPAD 40   // S_T row stride in bf16 units: 80B = 16B-aligned, 2-way bank alias only

typedef __attribute__((ext_vector_type(8))) short short8v;
typedef __attribute__((ext_vector_type(4))) float f32x4;

// Pack weight (Cout, Cin, K) fp32 -> bf16 A-fragments in exact lane-linear order:
// wf[((k*4 + c)*64 + l)*8 + j] = w[co = c*16 + (l&15)][ci = (l>>4)*8 + j][k]
__global__ void prep_w(const float* __restrict__ w, __hip_bfloat16* __restrict__ wf) {
    int idx = blockIdx.x * 256 + threadIdx.x;
    if (idx >= KK * 4 * 64 * 8) return;
    int j = idx & 7;
    int l = (idx >> 3) & 63;
    int c = (idx >> 9) & 3;
    int k = idx >> 11;
    int co = c * 16 + (l & 15);
    int ci = (l >> 4) * 8 + j;
    wf[idx] = __float2bfloat16(w[(co * CIN + ci) * KK + k]);
}

__launch_bounds__(256, 3)
__global__ void dcn3d(const float* __restrict__ x, const float* __restrict__ off,
                      const float* __restrict__ msk, const float* __restrict__ wsrc_f,
                      const __hip_bfloat16* __restrict__ wf,
                      const float* __restrict__ bias, float* __restrict__ out,
                      int use_wf) {
    // block -> (b, d, h)
    int blk = blockIdx.x;
    int h = blk % HH_;
    int t0 = blk / HH_;
    int d = t0 % DD_;
    int b = t0 / DD_;

    // packed bilinear params: x = po00|po01<<16, y = po10|po11<<16,
    //                         z = half2(pw00,pw01), w = half2(pw10,pw11)
    __shared__ uint4 Pp[KK * WW_];                    // 20736 B
    __shared__ __hip_bfloat16 S_T[2][WW_ * NPAD];     // 7680 B, [w][ci] transposed

    int tid = threadIdx.x;
    int lane = tid & 63;
    int wid = tid >> 6;

    // ---- Phase A: per-(k, w) bilinear parameters, packed ----
    for (int e = tid; e < KK * WW_; e += 256) {
        int k = e / WW_;
        int w = e - k * WW_;
        int kd = k / 9, kh = (k / 3) % 3, kw = k % 3;
        int dpos = d + kd - 1;
        bool vd = (dpos >= 0) && (dpos < DD_);
        int didx = min(max(dpos, 0), DD_ - 1);
        int sp = d * HWs + h * WW_ + w;
        int obase = (b * (2 * KK) + 2 * k) * DHW + sp;
        float oh = off[obase];
        float ow = off[obase + DHW];
        float m  = msk[(b * KK + k) * DHW + sp];
        float hh = (float)(kh + h - 1) + oh;
        float ww = (float)(kw + w - 1) + ow;
        float h0f = floorf(hh), w0f = floorf(ww);
        float lh = hh - h0f, lw = ww - w0f;
        int h0 = (int)h0f, w0 = (int)w0f;
        int h1 = h0 + 1, w1 = w0 + 1;
        bool ih0 = (h0 >= 0) && (h0 < HH_);
        bool ih1 = (h1 >= 0) && (h1 < HH_);
        bool iw0 = (w0 >= 0) && (w0 < WW_);
        bool iw1 = (w1 >= 0) && (w1 < WW_);
        int h0c = min(max(h0, 0), HH_ - 1), h1c = min(max(h1, 0), HH_ - 1);
        int w0c = min(max(w0, 0), WW_ - 1), w1c = min(max(w1, 0), WW_ - 1);
        float vm = vd ? m : 0.0f;
        float f00 = (ih0 && iw0) ? (1.0f - lh) * (1.0f - lw) * vm : 0.0f;
        float f01 = (ih0 && iw1) ? (1.0f - lh) * lw * vm : 0.0f;
        float f10 = (ih1 && iw0) ? lh * (1.0f - lw) * vm : 0.0f;
        float f11 = (ih1 && iw1) ? lh * lw * vm : 0.0f;
        int r0 = didx * HWs + h0c * WW_;
        int r1 = didx * HWs + h1c * WW_;
        uint4 P;
        P.x = (unsigned)(r0 + w0c) | ((unsigned)(r0 + w1c) << 16);
        P.y = (unsigned)(r1 + w0c) | ((unsigned)(r1 + w1c) << 16);
        __half2 ha = __floats2half2_rn(f00, f01);
        __half2 hb = __floats2half2_rn(f10, f11);
        P.z = *(const unsigned int*)&ha;
        P.w = *(const unsigned int*)&hb;
        Pp[e] = P;
    }

    f32x4 acc0 = {0.f, 0.f, 0.f, 0.f};
    f32x4 acc1 = acc0, acc2 = acc0;
    const float* xb = x + b * CIN * DHW;

    // A-fragment loader (lane-linear packed path, or scalar-gather fallback)
    auto loadA = [&](int k) -> short8v {
        if (use_wf) {
            return *(const short8v*)((const short*)wf + ((k * 4 + wid) * 64 + lane) * 8);
        } else {
            short8v a;
            int co = wid * 16 + (lane & 15);
            int ci0 = (lane >> 4) * 8;
#pragma unroll
            for (int j = 0; j < 8; ++j) {
                __hip_bfloat16 hv = __float2bfloat16(wsrc_f[(co * CIN + ci0 + j) * KK + k]);
                a[j] = *(const short*)&hv;
            }
            return a;
        }
    };
    short8v afrag = loadA(0);

    __syncthreads();   // Phase A done

    for (int k = 0; k < KK; ++k) {
        __hip_bfloat16* Sb = S_T[k & 1];
        // ---- sample S_k into LDS, transposed [w][ci], bf16 ----
#pragma unroll
        for (int it = 0; it < (CIN * WW_) / 256; ++it) {
            int e = tid + it * 256;
            int ci = e / WW_;
            int w = e - ci * WW_;
            uint4 P = Pp[k * WW_ + w];
            const float* xp = xb + ci * DHW;
            float2 wa = __half22float2(*(const __half2*)&P.z);
            float2 wb = __half22float2(*(const __half2*)&P.w);
            float v = wa.x * xp[P.x & 0xFFFFu] + wa.y * xp[P.x >> 16]
                    + wb.x * xp[P.y & 0xFFFFu] + wb.y * xp[P.y >> 16];
            Sb[w * NPAD + ci] = __float2bfloat16(v);
        }
        short8v anext = (k + 1 < KK) ? loadA(k + 1) : afrag;
        __syncthreads();
        // ---- MFMA: C[16co x 48w] strip per wave ----
        const short* Sbs = (const short*)Sb;
        int ciB = (lane >> 4) * 8;
        int wl = lane & 15;
        short8v b0 = *(const short8v*)(Sbs + (wl +  0) * NPAD + ciB);
        short8v b1 = *(const short8v*)(Sbs + (wl + 16) * NPAD + ciB);
        short8v b2 = *(const short8v*)(Sbs + (wl + 32) * NPAD + ciB);
        acc0 = __builtin_amdgcn_mfma_f32_16x16x32_bf16(afrag, b0, acc0, 0, 0, 0);
        acc1 = __builtin_amdgcn_mfma_f32_16x16x32_bf16(afrag, b1, acc1, 0, 0, 0);
        acc2 = __builtin_amdgcn_mfma_f32_16x16x32_bf16(afrag, b2, acc2, 0, 0, 0);
        afrag = anext;
    }

    // ---- epilogue: bias + store (C: col=lane&15 -> w, row=(lane>>4)*4+r -> co) ----
    int co = wid * 16 + (lane >> 4) * 4;
    int wl = lane & 15;
#pragma unroll
    for (int r = 0; r < 4; ++r) {
        float bv = bias[co + r];
        int ob = ((b * COUT + co + r) * DD_ + d) * HWs + h * WW_ + wl;
        out[ob +  0] = acc0[r] + bv;
        out[ob + 16] = acc1[r] + bv;
        out[ob + 32] = acc2[r] + bv;
    }
}

extern "C" void kernel_launch(void* const* d_in, const int* in_sizes, int n_in,
                              void* d_out, int out_size, void* d_ws, size_t ws_size,
                              hipStream_t stream) {
    const float* x    = (const float*)d_in[0];
    const float* off  = (const float*)d_in[1];
    const float* msk  = (const float*)d_in[2];
    const float* w    = (const float*)d_in[3];
    const float* bias = (const float*)d_in[4];
    float* out = (float*)d_out;

    const size_t WF_BYTES = (size_t)KK * 4 * 64 * 8 * sizeof(__hip_bfloat16); // 110592
    int use_wf = (ws_size >= WF_BYTES) ? 1 : 0;
    __hip_bfloat16* wf = (__hip_bfloat16*)d_ws;
    if (use_wf) {
        prep_w<<<(KK * 4 * 64 * 8 + 255) / 256, 256, 0, stream>>>(w, wf);
    }
    dcn3d<<<BSZ * DD_ * HH_, 256, 0, stream>>>(x, off, msk, w, wf, bias, out, use_wf);
}